// Round 2
// baseline (258.041 us; speedup 1.0000x reference)
//
#include <hip/hip_runtime.h>

#define BB 32
#define SS 1024
#define DD 256
#define KB 32
#define TILE 64

// out[b,a,c] = sum_s w[b,s] * v[b,s,a] * conj(v[b,s,c]),  v = r + j*i
// out_r = P1 + P2 (symmetric), out_i = P3 + P1 - P2 (antisymmetric)
// P1 = sum w*r_a*r_c, P2 = sum w*i_a*i_c, P3 = sum w*(i_a - r_a)*(r_c + i_c)

extern "C" __global__ void __launch_bounds__(256)
cmix_kernel(const float* __restrict__ real, const float* __restrict__ imag,
            const float* __restrict__ wts, float* __restrict__ out) {
    __shared__ float s_wr[KB][TILE];
    __shared__ float s_wi[KB][TILE];
    __shared__ float s_wt[KB][TILE];
    __shared__ float s_cr[KB][TILE];
    __shared__ float s_ci[KB][TILE];
    __shared__ float s_ct[KB][TILE];

    // XCD-aware mapping: grid = 320 = 8 XCDs x 40 slots; blocks are dispatched
    // round-robin over XCDs by blockIdx, so slot = bx>>3 keeps each batch's 10
    // tiles on ONE XCD (4 batches/XCD) -> panel re-reads hit that XCD's L2.
    const int bx   = blockIdx.x;
    const int xcd  = bx & 7;
    const int slot = bx >> 3;          // 0..39
    const int b    = xcd * 4 + slot / 10;
    const int t    = slot % 10;

    // 10 upper-triangular 64x64 tiles, tables bit-packed (no scratch array)
    const int ta = (int)((0x3221110000ULL >> (4 * t)) & 15);
    const int tc = (int)((0x3323213210ULL >> (4 * t)) & 15);
    const int a0 = ta * TILE;
    const int c0 = tc * TILE;

    const int tid = threadIdx.x;
    const int ty  = tid >> 4;   // 0..15 -> a sub-tile
    const int tx  = tid & 15;   // 0..15 -> c sub-tile

    const float* rb = real + (size_t)b * SS * DD;
    const float* ib = imag + (size_t)b * SS * DD;
    const float* wb = wts  + (size_t)b * SS;

    float p1[4][4] = {};
    float p2[4][4] = {};
    float p3[4][4] = {};

    for (int s0 = 0; s0 < SS; s0 += KB) {
        __syncthreads();
        // ---- stage KB x 64 panels (a-side weighted, c-side raw) ----
        #pragma unroll
        for (int it = 0; it < 2; ++it) {
            int pos = tid + it * 256;          // over KB*16 = 512 float4 slots
            int row = pos >> 4;                // k within chunk
            int col = (pos & 15) << 2;         // float offset within 64
            int s   = s0 + row;
            float w = wb[s];
            const float4 ra = *(const float4*)(rb + s * DD + a0 + col);
            const float4 ia = *(const float4*)(ib + s * DD + a0 + col);
            const float4 rc = *(const float4*)(rb + s * DD + c0 + col);
            const float4 ic = *(const float4*)(ib + s * DD + c0 + col);
            float4 v;
            v.x = w*ra.x; v.y = w*ra.y; v.z = w*ra.z; v.w = w*ra.w;
            *(float4*)&s_wr[row][col] = v;
            v.x = w*ia.x; v.y = w*ia.y; v.z = w*ia.z; v.w = w*ia.w;
            *(float4*)&s_wi[row][col] = v;
            v.x = w*(ia.x-ra.x); v.y = w*(ia.y-ra.y); v.z = w*(ia.z-ra.z); v.w = w*(ia.w-ra.w);
            *(float4*)&s_wt[row][col] = v;
            *(float4*)&s_cr[row][col] = rc;
            *(float4*)&s_ci[row][col] = ic;
            v.x = rc.x+ic.x; v.y = rc.y+ic.y; v.z = rc.z+ic.z; v.w = rc.w+ic.w;
            *(float4*)&s_ct[row][col] = v;
        }
        __syncthreads();

        // ---- inner product over the chunk ----
        #pragma unroll 8
        for (int k = 0; k < KB; ++k) {
            const float4 ar = *(const float4*)&s_wr[k][ty*4];
            const float4 ai = *(const float4*)&s_wi[k][ty*4];
            const float4 at = *(const float4*)&s_wt[k][ty*4];
            const float4 cr = *(const float4*)&s_cr[k][tx*4];
            const float4 ci = *(const float4*)&s_ci[k][tx*4];
            const float4 ct = *(const float4*)&s_ct[k][tx*4];
            const float arr[4] = {ar.x, ar.y, ar.z, ar.w};
            const float aii[4] = {ai.x, ai.y, ai.z, ai.w};
            const float att[4] = {at.x, at.y, at.z, at.w};
            const float crr[4] = {cr.x, cr.y, cr.z, cr.w};
            const float cii[4] = {ci.x, ci.y, ci.z, ci.w};
            const float ctt[4] = {ct.x, ct.y, ct.z, ct.w};
            #pragma unroll
            for (int aa = 0; aa < 4; ++aa) {
                #pragma unroll
                for (int cc = 0; cc < 4; ++cc) {
                    p1[aa][cc] = fmaf(arr[aa], crr[cc], p1[aa][cc]);
                    p2[aa][cc] = fmaf(aii[aa], cii[cc], p2[aa][cc]);
                    p3[aa][cc] = fmaf(att[aa], ctt[cc], p3[aa][cc]);
                }
            }
        }
    }

    // ---- epilogue: combine + write (and mirrored tile if off-diagonal) ----
    float orr[4][4], oii[4][4];
    #pragma unroll
    for (int aa = 0; aa < 4; ++aa)
        #pragma unroll
        for (int cc = 0; cc < 4; ++cc) {
            orr[aa][cc] = p1[aa][cc] + p2[aa][cc];
            oii[aa][cc] = p3[aa][cc] + p1[aa][cc] - p2[aa][cc];
        }

    float* outR = out + (size_t)b * DD * DD;
    float* outI = out + (size_t)BB * DD * DD + (size_t)b * DD * DD;
    const int arow = a0 + ty * 4;
    const int ccol = c0 + tx * 4;

    #pragma unroll
    for (int aa = 0; aa < 4; ++aa) {
        float4 vr = { orr[aa][0], orr[aa][1], orr[aa][2], orr[aa][3] };
        float4 vi = { oii[aa][0], oii[aa][1], oii[aa][2], oii[aa][3] };
        *(float4*)(outR + (size_t)(arow + aa) * DD + ccol) = vr;
        *(float4*)(outI + (size_t)(arow + aa) * DD + ccol) = vi;
    }
    if (a0 != c0) {
        // out_r symmetric, out_i antisymmetric
        #pragma unroll
        for (int cc = 0; cc < 4; ++cc) {
            float4 vr = { orr[0][cc], orr[1][cc], orr[2][cc], orr[3][cc] };
            float4 vi = { -oii[0][cc], -oii[1][cc], -oii[2][cc], -oii[3][cc] };
            *(float4*)(outR + (size_t)(ccol + cc) * DD + arow) = vr;
            *(float4*)(outI + (size_t)(ccol + cc) * DD + arow) = vi;
        }
    }
}

extern "C" void kernel_launch(void* const* d_in, const int* in_sizes, int n_in,
                              void* d_out, int out_size, void* d_ws, size_t ws_size,
                              hipStream_t stream) {
    const float* real = (const float*)d_in[0];
    const float* imag = (const float*)d_in[1];
    const float* wts  = (const float*)d_in[2];
    float* out = (float*)d_out;
    dim3 grid(BB * 10);   // 8 XCDs x 40 slots = 32 batches x 10 triangular tiles
    dim3 block(256);
    cmix_kernel<<<grid, block, 0, stream>>>(real, imag, wts, out);
}

// Round 4
// 159.900 us; speedup vs baseline: 1.6138x; 1.6138x over previous
//
#include <hip/hip_runtime.h>

typedef __attribute__((ext_vector_type(8))) short s8v;      // 8 bf16 (4 VGPR) MFMA operand
typedef __attribute__((ext_vector_type(16))) float f32x16;  // 32x32 MFMA accumulator

#define BB 32
#define SS 1024
#define DD 256
#define KB 64            // s-values staged per chunk
#define LSTR 72          // padded s-stride in shorts (144B: 16B-aligned, 2-way-free reads)
#define PSZ (64 * LSTR)  // plane size in shorts

// out[b,a,c] = sum_s w * v_a * conj(v_c), v = r + j*i
// a-side planes (w-folded, hi/lo split): wr_h, wr_l, wi_h, wi_l
// c-side planes (RNE bf16):             r_c, i_c
// out_r = (wr_h+wr_l) x r_c + (wi_h+wi_l) x i_c
// out_i = (wi_h+wi_l) x r_c - (wr_h+wr_l) x i_c   (second term in acc_x, subtract at end)

__device__ __forceinline__ unsigned short bf16rn(float v) {
    unsigned b = __float_as_uint(v);
    return (unsigned short)((b + 0x7FFFu + ((b >> 16) & 1u)) >> 16);
}

extern "C" __global__ void __launch_bounds__(256, 2)
cmix3_kernel(const float* __restrict__ real, const float* __restrict__ imag,
             const float* __restrict__ wts, float* __restrict__ out) {
    __shared__ unsigned short lds[6 * PSZ];   // 55.3 KB -> 2 blocks/CU

    // XCD swizzle: 512 = 8 XCDs x 64 slots; 4 batches per XCD (L2 reuse of r,i panels)
    const int bx   = blockIdx.x;
    const int xcd  = bx & 7;
    const int slot = bx >> 3;                 // 0..63
    const int b    = xcd * 4 + (slot >> 4);   // 0..31
    const int t    = slot & 15;               // 16 tiles of 64x64
    const int a0   = (t >> 2) * 64;
    const int c0   = (t & 3) * 64;

    const int tid = threadIdx.x;
    const int wid = tid >> 6;
    const int l   = tid & 63;

    // staging role: waves 0,1 stage a-side (real, imag); waves 2,3 stage c-side
    const int  fgrp = (l >> 2) & 15;          // 16 feat-quads
    const int  sgrp = l & 3;                  // 4 s-groups of 16
    const bool isA  = (wid < 2);
    const float* srcArr = ((wid & 1) ? imag : real)
                        + (size_t)b * SS * DD + (isA ? a0 : c0) + fgrp * 4;
    const float* wb = wts + (size_t)b * SS;

    // compute role: wave grid 2x2 of 32x32 subtiles
    const int m0  = (wid >> 1) * 32;
    const int n0  = (wid & 1) * 32;
    const int fr  = l & 31;
    const int hi8 = (l >> 5) * 8;

    const int pA = wid * 2 * PSZ;             // wave0 -> planes 0/1, wave1 -> 2/3
    const int pC = (4 + (wid & 1)) * PSZ;     // wave2 -> plane 4 (r), wave3 -> 5 (i)

    f32x16 accr = {}, acci = {}, accx = {};

    for (int ch = 0; ch < 16; ++ch) {
        const int s0 = ch * KB;
        __syncthreads();                       // prev compute done before overwrite
        const int sb = s0 + sgrp * 16;

        if (isA) {
            #pragma unroll
            for (int hb = 0; hb < 2; ++hb) {   // two half-batches of 8 s (reg pressure)
                const int sh = sb + hb * 8;
                const float4 w1 = *(const float4*)(wb + sh);
                const float4 w2 = *(const float4*)(wb + sh + 4);
                const float wv[8] = {w1.x,w1.y,w1.z,w1.w,w2.x,w2.y,w2.z,w2.w};
                unsigned hw[4][4], lw[4][4];
                #pragma unroll
                for (int si = 0; si < 8; ++si) {
                    const float4 x = *(const float4*)(srcArr + (size_t)(sh + si) * DD);
                    const float ww = wv[si];
                    const float y[4] = {x.x*ww, x.y*ww, x.z*ww, x.w*ww};
                    #pragma unroll
                    for (int e = 0; e < 4; ++e) {
                        unsigned yb   = __float_as_uint(y[e]);
                        unsigned hb32 = yb & 0xFFFF0000u;            // truncated hi
                        float    lo   = y[e] - __uint_as_float(hb32); // exact residual
                        unsigned hs   = hb32 >> 16;
                        unsigned ls   = __float_as_uint(lo) >> 16;    // truncated lo
                        if (si & 1) { hw[e][si>>1] |= hs << 16; lw[e][si>>1] |= ls << 16; }
                        else        { hw[e][si>>1]  = hs;       lw[e][si>>1]  = ls; }
                    }
                }
                #pragma unroll
                for (int e = 0; e < 4; ++e) {
                    const int off = (fgrp*4 + e) * LSTR + sgrp*16 + hb*8;
                    uint4 vh = {hw[e][0], hw[e][1], hw[e][2], hw[e][3]};
                    uint4 vl = {lw[e][0], lw[e][1], lw[e][2], lw[e][3]};
                    *(uint4*)&lds[pA + off]       = vh;
                    *(uint4*)&lds[pA + PSZ + off] = vl;
                }
            }
        } else {
            #pragma unroll
            for (int hb = 0; hb < 2; ++hb) {
                const int sh = sb + hb * 8;
                unsigned cw[4][4];
                #pragma unroll
                for (int si = 0; si < 8; ++si) {
                    const float4 x = *(const float4*)(srcArr + (size_t)(sh + si) * DD);
                    const float y[4] = {x.x, x.y, x.z, x.w};
                    #pragma unroll
                    for (int e = 0; e < 4; ++e) {
                        unsigned cs = bf16rn(y[e]);                   // RNE (unbiased)
                        if (si & 1) cw[e][si>>1] |= cs << 16; else cw[e][si>>1] = cs;
                    }
                }
                #pragma unroll
                for (int e = 0; e < 4; ++e) {
                    const int off = (fgrp*4 + e) * LSTR + sgrp*16 + hb*8;
                    uint4 v = {cw[e][0], cw[e][1], cw[e][2], cw[e][3]};
                    *(uint4*)&lds[pC + off] = v;
                }
            }
        }
        __syncthreads();

        // ---- compute: 4 k-steps of K=16; both operands same [feat][s] addressing
        //      (k-permutation-safe); A: m = l&31 -> a-feat, B: n = l&31 -> c-feat
        #pragma unroll
        for (int kk = 0; kk < 4; ++kk) {
            const int ko = kk * 16 + hi8;
            const int ra = (m0 + fr) * LSTR + ko;
            const int rc = (n0 + fr) * LSTR + ko;
            s8v A1 = *(const s8v*)&lds[0*PSZ + ra];   // wr_h
            s8v A2 = *(const s8v*)&lds[1*PSZ + ra];   // wr_l
            s8v A3 = *(const s8v*)&lds[2*PSZ + ra];   // wi_h
            s8v A4 = *(const s8v*)&lds[3*PSZ + ra];   // wi_l
            s8v C1 = *(const s8v*)&lds[4*PSZ + rc];   // r_c
            s8v C2 = *(const s8v*)&lds[5*PSZ + rc];   // i_c
            accr = __builtin_amdgcn_mfma_f32_32x32x16_bf16(A1, C1, accr, 0, 0, 0);
            accr = __builtin_amdgcn_mfma_f32_32x32x16_bf16(A2, C1, accr, 0, 0, 0);
            accr = __builtin_amdgcn_mfma_f32_32x32x16_bf16(A3, C2, accr, 0, 0, 0);
            accr = __builtin_amdgcn_mfma_f32_32x32x16_bf16(A4, C2, accr, 0, 0, 0);
            acci = __builtin_amdgcn_mfma_f32_32x32x16_bf16(A3, C1, acci, 0, 0, 0);
            acci = __builtin_amdgcn_mfma_f32_32x32x16_bf16(A4, C1, acci, 0, 0, 0);
            accx = __builtin_amdgcn_mfma_f32_32x32x16_bf16(A1, C2, accx, 0, 0, 0);
            accx = __builtin_amdgcn_mfma_f32_32x32x16_bf16(A2, C2, accx, 0, 0, 0);
        }
    }

    // ---- epilogue: C/D layout col=lane&31, row=(reg&3)+8*(reg>>2)+4*(lane>>5)
    float* outR = out + (size_t)b * DD * DD;
    float* outI = out + (size_t)BB * DD * DD + (size_t)b * DD * DD;
    const int col = c0 + n0 + (l & 31);
    #pragma unroll
    for (int g = 0; g < 4; ++g) {
        #pragma unroll
        for (int q = 0; q < 4; ++q) {
            const int reg = g * 4 + q;
            const int row = a0 + m0 + q + 8 * g + 4 * (l >> 5);
            outR[(size_t)row * DD + col] = accr[reg];
            outI[(size_t)row * DD + col] = acci[reg] - accx[reg];
        }
    }
}

extern "C" void kernel_launch(void* const* d_in, const int* in_sizes, int n_in,
                              void* d_out, int out_size, void* d_ws, size_t ws_size,
                              hipStream_t stream) {
    const float* real = (const float*)d_in[0];
    const float* imag = (const float*)d_in[1];
    const float* wts  = (const float*)d_in[2];
    float* out = (float*)d_out;
    dim3 grid(512);    // 8 XCDs x (4 batches x 16 tiles)
    dim3 block(256);
    cmix3_kernel<<<grid, block, 0, stream>>>(real, imag, wts, out);
}

// Round 7
// 155.820 us; speedup vs baseline: 1.6560x; 1.0262x over previous
//
#include <hip/hip_runtime.h>

typedef __attribute__((ext_vector_type(8))) short s8v;      // 8 bf16 (4 VGPR) MFMA operand
typedef __attribute__((ext_vector_type(16))) float f32x16;  // 32x32 MFMA accumulator

#define BB 32
#define SS 1024
#define DD 256
#define KB 32              // s-values per chunk
#define NCH (SS / KB)      // 32 chunks
#define LSTR 40            // s-stride in shorts = 80B: span stride 5 (coprime 8) ->
                           // bank-uniform reads AND writes at the 8-words/bank floor
#define PSZ (64 * LSTR)    // plane: 64 feats x LSTR
#define BUFS (6 * PSZ)     // 6 planes per buffer

// out[b,a,c] = sum_s w * v_a * conj(v_c), v = r + j*i
// a-side planes (w-folded, hi/lo split): wr_h, wr_l, wi_h, wi_l
// c-side planes (RNE bf16):             r_c, i_c
// out_r = (wr_h+wr_l) x r_c + (wi_h+wi_l) x i_c
// out_i = (wi_h+wi_l) x r_c - (wr_h+wr_l) x i_c   (x-term in accx, subtract at end)

__device__ __forceinline__ unsigned short bf16rn(float v) {
    unsigned b = __float_as_uint(v);
    return (unsigned short)((b + 0x7FFFu + ((b >> 16) & 1u)) >> 16);
}

extern "C" __global__ void __launch_bounds__(256, 2)
cmix4_kernel(const float* __restrict__ real, const float* __restrict__ imag,
             const float* __restrict__ wts, float* __restrict__ out) {
    __shared__ unsigned short lds[2 * BUFS];   // 61440 B -> 2 blocks/CU

    // XCD swizzle: 512 = 8 XCDs x 64 slots; 4 batches per XCD (L2 reuse)
    const int bx   = blockIdx.x;
    const int xcd  = bx & 7;
    const int slot = bx >> 3;
    const int b    = xcd * 4 + (slot >> 4);
    const int t    = slot & 15;
    const int a0   = (t >> 2) * 64;
    const int c0   = (t & 3) * 64;

    const int tid = threadIdx.x;
    const int wid = tid >> 6;
    const int l   = tid & 63;

    // staging role: wave0->wr(h,l), wave1->wi(h,l), wave2->r_c, wave3->i_c
    const int  fgrp = l >> 2;     // 16 feat-quads
    const int  sgrp = l & 3;      // 4 s-groups of 8
    const bool isA  = (wid < 2);
    const float* srcA = ((wid & 1) ? imag : real)
                      + (size_t)b * SS * DD + (isA ? a0 : c0) + fgrp * 4;
    const float* wb = wts + (size_t)b * SS;
    const int pA   = wid * 2 * PSZ;           // hi plane; lo at +PSZ
    const int pC   = (4 + (wid & 1)) * PSZ;
    const int woff = fgrp * 4 * LSTR + sgrp * 8;

    // compute role: 2x2 wave grid of 32x32 subtiles
    const int m0  = (wid >> 1) * 32;
    const int n0  = (wid & 1) * 32;
    const int fr  = l & 31;
    const int hi8 = (l >> 5) * 8;

    f32x16 accr = {}, acci = {}, accx = {};
    float4 xr[8];   // in-flight staged rows (static-indexed only)

    auto stage_load = [&](int sch) {
        const int sh = sch + sgrp * 8;
        #pragma unroll
        for (int si = 0; si < 8; ++si)
            xr[si] = *(const float4*)(srcA + (size_t)(sh + si) * DD);
    };

    auto stage_store = [&](unsigned short* buf, int sch) {
        const int sh = sch + sgrp * 8;
        if (isA) {
            const float4 w1 = *(const float4*)(wb + sh);
            const float4 w2 = *(const float4*)(wb + sh + 4);
            const float wv[8] = {w1.x,w1.y,w1.z,w1.w,w2.x,w2.y,w2.z,w2.w};
            unsigned hw[4][4], lw[4][4];
            #pragma unroll
            for (int si = 0; si < 8; ++si) {
                const float y[4] = {xr[si].x*wv[si], xr[si].y*wv[si],
                                    xr[si].z*wv[si], xr[si].w*wv[si]};
                #pragma unroll
                for (int e = 0; e < 4; ++e) {
                    unsigned yb   = __float_as_uint(y[e]);
                    unsigned hb32 = yb & 0xFFFF0000u;             // truncated hi
                    float    lo   = y[e] - __uint_as_float(hb32); // exact residual
                    unsigned hs   = hb32 >> 16;
                    unsigned ls   = __float_as_uint(lo) >> 16;
                    if (si & 1) { hw[e][si>>1] |= hs << 16; lw[e][si>>1] |= ls << 16; }
                    else        { hw[e][si>>1]  = hs;       lw[e][si>>1]  = ls; }
                }
            }
            #pragma unroll
            for (int e = 0; e < 4; ++e) {
                uint4 vh = {hw[e][0], hw[e][1], hw[e][2], hw[e][3]};
                uint4 vl = {lw[e][0], lw[e][1], lw[e][2], lw[e][3]};
                *(uint4*)&buf[pA + woff + e * LSTR]       = vh;
                *(uint4*)&buf[pA + PSZ + woff + e * LSTR] = vl;
            }
        } else {
            unsigned cw[4][4];
            #pragma unroll
            for (int si = 0; si < 8; ++si) {
                const float y[4] = {xr[si].x, xr[si].y, xr[si].z, xr[si].w};
                #pragma unroll
                for (int e = 0; e < 4; ++e) {
                    unsigned cs = bf16rn(y[e]);                   // RNE (unbiased)
                    if (si & 1) cw[e][si>>1] |= cs << 16; else cw[e][si>>1] = cs;
                }
            }
            #pragma unroll
            for (int e = 0; e < 4; ++e) {
                uint4 v = {cw[e][0], cw[e][1], cw[e][2], cw[e][3]};
                *(uint4*)&buf[pC + woff + e * LSTR] = v;
            }
        }
    };

    // ---- prologue: stage chunk 0 into buf0 ----
    stage_load(0);
    stage_store(lds, 0);
    __syncthreads();

    // ---- main loop: issue loads early, MFMA, convert+write late (T14) ----
    for (int ch = 0; ch < NCH; ++ch) {
        unsigned short* bc = lds + (ch & 1) * BUFS;          // compute buffer
        unsigned short* bs = lds + ((ch & 1) ^ 1) * BUFS;    // stage buffer
        const bool more = (ch + 1 < NCH);
        if (more) stage_load((ch + 1) * KB);

        #pragma unroll
        for (int kk = 0; kk < 2; ++kk) {
            const int ko = kk * 16 + hi8;
            const int ra = (m0 + fr) * LSTR + ko;
            const int rc = (n0 + fr) * LSTR + ko;
            s8v A1 = *(const s8v*)&bc[0*PSZ + ra];   // wr_h
            s8v A2 = *(const s8v*)&bc[1*PSZ + ra];   // wr_l
            s8v A3 = *(const s8v*)&bc[2*PSZ + ra];   // wi_h
            s8v A4 = *(const s8v*)&bc[3*PSZ + ra];   // wi_l
            s8v C1 = *(const s8v*)&bc[4*PSZ + rc];   // r_c
            s8v C2 = *(const s8v*)&bc[5*PSZ + rc];   // i_c
            accr = __builtin_amdgcn_mfma_f32_32x32x16_bf16(A1, C1, accr, 0, 0, 0);
            accr = __builtin_amdgcn_mfma_f32_32x32x16_bf16(A2, C1, accr, 0, 0, 0);
            accr = __builtin_amdgcn_mfma_f32_32x32x16_bf16(A3, C2, accr, 0, 0, 0);
            accr = __builtin_amdgcn_mfma_f32_32x32x16_bf16(A4, C2, accr, 0, 0, 0);
            acci = __builtin_amdgcn_mfma_f32_32x32x16_bf16(A3, C1, acci, 0, 0, 0);
            acci = __builtin_amdgcn_mfma_f32_32x32x16_bf16(A4, C1, acci, 0, 0, 0);
            accx = __builtin_amdgcn_mfma_f32_32x32x16_bf16(A1, C2, accx, 0, 0, 0);
            accx = __builtin_amdgcn_mfma_f32_32x32x16_bf16(A2, C2, accx, 0, 0, 0);
        }

        if (more) stage_store(bs, (ch + 1) * KB);
        __syncthreads();
    }

    // ---- epilogue: C/D layout col=lane&31, row=(reg&3)+8*(reg>>2)+4*(lane>>5)
    float* outR = out + (size_t)b * DD * DD;
    float* outI = out + (size_t)BB * DD * DD + (size_t)b * DD * DD;
    const int col = c0 + n0 + (l & 31);
    #pragma unroll
    for (int g = 0; g < 4; ++g) {
        #pragma unroll
        for (int q = 0; q < 4; ++q) {
            const int reg = g * 4 + q;
            const int row = a0 + m0 + q + 8 * g + 4 * (l >> 5);
            outR[(size_t)row * DD + col] = accr[reg];
            outI[(size_t)row * DD + col] = acci[reg] - accx[reg];
        }
    }
}

extern "C" void kernel_launch(void* const* d_in, const int* in_sizes, int n_in,
                              void* d_out, int out_size, void* d_ws, size_t ws_size,
                              hipStream_t stream) {
    const float* real = (const float*)d_in[0];
    const float* imag = (const float*)d_in[1];
    const float* wts  = (const float*)d_in[2];
    float* out = (float*)d_out;
    dim3 grid(512);    // 8 XCDs x (4 batches x 16 tiles) = 2 blocks/CU exactly
    dim3 block(256);
    cmix4_kernel<<<grid, block, 0, stream>>>(real, imag, wts, out);
}